// Round 6
// baseline (34.063 us; speedup 1.0000x reference)
//
#include <hip/hip_runtime.h>

// out[b, m] = sum_n exp(-0.5 * ||inputs[b,n] - stars[m]||^2)
// B=32, N=4096, M=1024, D=3, fp32 in/out.
//
// exp(-0.5*d2) = E_n * 2^(Sx*x + Sy*y + Sz*z + K), E_n = 2^(-C2*||x||^2).
// R5 post-mortem: ~19us additive offset independent of VALU count; prime
// suspect is the LDS unit (2048 uniform ds_read_b128 per CU, serialized).
// This round: NO LDS AT ALL. The point stream is wave-uniform (blockIdx +
// loop counter only) -> compiler scalarizes to s_load on the idle SMEM pipe.
// E recomputed inline per pair (+8 VALU ops amortized over 4 stars).
// Hot loop per pair per star: 3 pk_fma (dot) + 2 v_exp_f32 + 1 pk_fma (acc).

typedef float f32x2 __attribute__((ext_vector_type(2)));

#define NB 32
#define NN 4096
#define NM 1024
#define NCHUNK 32               // blocks per batch along N
#define NPB (NN / NCHUNK)       // 128 points per block
#define NPAIR (NPB / 2)         // 64 packed pairs
#define TPB 256                 // threads per block (4 waves)
#define MPT (NM / TPB)          // 4 stars per thread

__device__ __forceinline__ float exp2_hw(float x) {
    float r;
    asm("v_exp_f32 %0, %1" : "=v"(r) : "v"(x));
    return r;
}

__device__ __forceinline__ f32x2 pk_fma(f32x2 a, f32x2 b, f32x2 c) {
    f32x2 d;
    asm("v_pk_fma_f32 %0, %1, %2, %3" : "=v"(d) : "v"(a), "v"(b), "v"(c));
    return d;
}

__global__ __launch_bounds__(TPB, 4) void gau_part(const float* __restrict__ inputs,
                                                   const float* __restrict__ stars,
                                                   float* __restrict__ part) {
    constexpr float C2  = 0.72134752044448169f;  // 0.5*log2(e)
    constexpr float L2E = 1.44269504088896340f;  // log2(e)

    const int b     = blockIdx.x / NCHUNK;
    const int chunk = blockIdx.x % NCHUNK;
    const int t     = threadIdx.x;

    // Per-thread star constants (per-lane VGPR loads, L2-resident 12KB)
    f32x2 Sx2[MPT], Sy2[MPT], Sz2[MPT], K2[MPT], acc[MPT];
#pragma unroll
    for (int k = 0; k < MPT; ++k) {
        int m = t + k * TPB;
        float sx = stars[3 * m + 0];
        float sy = stars[3 * m + 1];
        float sz = stars[3 * m + 2];
        float a = L2E * sx, c = L2E * sy, e = L2E * sz;
        float kk = -C2 * (sx * sx + sy * sy + sz * sz);
        Sx2[k] = f32x2{a, a};
        Sy2[k] = f32x2{c, c};
        Sz2[k] = f32x2{e, e};
        K2[k]  = f32x2{kk, kk};
        acc[k] = f32x2{0.0f, 0.0f};
    }

    // Wave-uniform point stream: address depends only on blockIdx + i
    // -> compiler emits scalar (s_load) reads on the SMEM pipe. No LDS.
    const float* pp = inputs + ((size_t)b * NN + (size_t)chunk * NPB) * 3;

#pragma unroll 4
    for (int i = 0; i < NPAIR; ++i) {
        float x0 = pp[6 * i + 0], y0 = pp[6 * i + 1], z0 = pp[6 * i + 2];
        float x1 = pp[6 * i + 3], y1 = pp[6 * i + 4], z1 = pp[6 * i + 5];
        float q0 = -C2 * x0 * x0 - C2 * y0 * y0 - C2 * z0 * z0;
        float q1 = -C2 * x1 * x1 - C2 * y1 * y1 - C2 * z1 * z1;
        f32x2 E2 = f32x2{exp2_hw(q0), exp2_hw(q1)};
        f32x2 x2 = f32x2{x0, x1};
        f32x2 y2 = f32x2{y0, y1};
        f32x2 z2 = f32x2{z0, z1};
#pragma unroll
        for (int k = 0; k < MPT; ++k) {
            f32x2 inner = pk_fma(Sx2[k], x2, pk_fma(Sy2[k], y2, pk_fma(Sz2[k], z2, K2[k])));
            f32x2 e2 = f32x2{exp2_hw(inner.x), exp2_hw(inner.y)};
            acc[k] = pk_fma(E2, e2, acc[k]);
        }
    }

    // Coalesced partial store: part[(b*NCHUNK + chunk)*NM + m]
    float* pb = part + ((size_t)b * NCHUNK + chunk) * NM;
#pragma unroll
    for (int k = 0; k < MPT; ++k) {
        pb[t + k * TPB] = acc[k].x + acc[k].y;
    }
}

__global__ __launch_bounds__(256) void gau_reduce(const float* __restrict__ part,
                                                  float* __restrict__ out) {
    const int o = blockIdx.x * 256 + threadIdx.x;  // o = b*NM + m, 32K total
    const int b = o >> 10;
    const int m = o & (NM - 1);
    const float* pb = part + (size_t)b * NCHUNK * NM + m;
    float s = 0.0f;
#pragma unroll
    for (int c = 0; c < NCHUNK; ++c) {
        s += pb[(size_t)c * NM];  // adjacent lanes -> adjacent m: coalesced
    }
    out[o] = s;
}

extern "C" void kernel_launch(void* const* d_in, const int* in_sizes, int n_in,
                              void* d_out, int out_size, void* d_ws, size_t ws_size,
                              hipStream_t stream) {
    const float* inputs = (const float*)d_in[0];  // (32, 4096, 3)
    const float* stars  = (const float*)d_in[1];  // (1024, 3)
    float* out  = (float*)d_out;                  // (32, 1024)
    float* part = (float*)d_ws;                   // (32*32, 1024) = 4 MB

    gau_part<<<NB * NCHUNK, TPB, 0, stream>>>(inputs, stars, part);
    gau_reduce<<<(NB * NM) / 256, 256, 0, stream>>>(part, out);
}